// Round 1
// baseline (1646.111 us; speedup 1.0000x reference)
//
#include <hip/hip_runtime.h>
#include <hip/hip_bf16.h>

#define B_ 4
#define S_ 2048
#define D_ 512
#define H_ 8
#define DH_ 64
#define EPS_ -50000.0f

// ---------------------------------------------------------------------------
// Kernel A: flash-style attention, fp32.
// grid = B*H*(S/64) = 1024 blocks, 256 threads.
// Each block: one (b, h, 64-query tile). Thread (ql, i8): queries ql and
// ql+32, key-group k = kk*8 + i8 within each 64-key tile, dims i8*8..i8*8+7.
// ---------------------------------------------------------------------------
__global__ __launch_bounds__(256, 2) void attn_fp32_kernel(
    const float* __restrict__ qv, const float* __restrict__ km,
    const float* __restrict__ vm, const int* __restrict__ mask,
    const float* __restrict__ cut, float* __restrict__ att)
{
    __shared__ float sK[64][68];
    __shared__ float sV[64][68];
    __shared__ float sP[64][68];
    __shared__ float sCut[64];
    __shared__ int   sMask[64];

    const int nqt = S_ / 64;            // 32 query tiles
    const int bid = blockIdx.x;
    const int qt  = bid % nqt;
    const int h   = (bid / nqt) % H_;
    const int b   = bid / (nqt * H_);
    const int q0  = qt * 64;

    const int tid = threadIdx.x;
    const int ql  = tid >> 3;           // 0..31
    const int i8  = tid & 7;            // 0..7

    // Q rows for the two queries this thread owns (64 floats each, in regs)
    float4 qA[16], qB[16];
    {
        const float4* ra = reinterpret_cast<const float4*>(
            qv + ((size_t)(b * S_ + q0 + ql)) * D_ + h * DH_);
        const float4* rb = reinterpret_cast<const float4*>(
            qv + ((size_t)(b * S_ + q0 + ql + 32)) * D_ + h * DH_);
#pragma unroll
        for (int j = 0; j < 16; ++j) { qA[j] = ra[j]; qB[j] = rb[j]; }
    }

    float accA[8], accB[8];
#pragma unroll
    for (int j = 0; j < 8; ++j) { accA[j] = 0.f; accB[j] = 0.f; }
    float mA = -INFINITY, mB = -INFINITY, lA = 0.f, lB = 0.f;

    for (int kt = 0; kt < S_ / 64; ++kt) {
        const int k0 = kt * 64;
        __syncthreads();   // previous tile's LDS reads done
        // stage K, V tiles (64 rows x 64 floats each)
#pragma unroll
        for (int j = 0; j < 4; ++j) {
            const int li = tid + j * 256;       // 0..1023
            const int r  = li >> 4;             // row 0..63
            const int c4 = (li & 15) * 4;       // col 0..60 step 4
            const size_t g = ((size_t)(b * S_ + k0 + r)) * D_ + h * DH_ + c4;
            *reinterpret_cast<float4*>(&sK[r][c4]) =
                *reinterpret_cast<const float4*>(km + g);
            *reinterpret_cast<float4*>(&sV[r][c4]) =
                *reinterpret_cast<const float4*>(vm + g);
        }
        if (tid < 64)       sMask[tid]      = mask[(size_t)b * S_ + k0 + tid];
        else if (tid < 128) sCut[tid - 64]  = cut[(size_t)b * S_ + k0 + tid - 64];
        __syncthreads();

        // scores for 8 keys x 2 queries
        float pA[8], pB[8];
        float mxA = -INFINITY, mxB = -INFINITY;
#pragma unroll
        for (int kk = 0; kk < 8; ++kk) {
            const int k = kk * 8 + i8;
            const float4* kr = reinterpret_cast<const float4*>(&sK[k][0]);
            float4 da = make_float4(0.f, 0.f, 0.f, 0.f);
            float4 db = make_float4(0.f, 0.f, 0.f, 0.f);
#pragma unroll
            for (int j = 0; j < 16; ++j) {
                const float4 kvv = kr[j];
                da.x = fmaf(qA[j].x, kvv.x, da.x);
                da.y = fmaf(qA[j].y, kvv.y, da.y);
                da.z = fmaf(qA[j].z, kvv.z, da.z);
                da.w = fmaf(qA[j].w, kvv.w, da.w);
                db.x = fmaf(qB[j].x, kvv.x, db.x);
                db.y = fmaf(qB[j].y, kvv.y, db.y);
                db.z = fmaf(qB[j].z, kvv.z, db.z);
                db.w = fmaf(qB[j].w, kvv.w, db.w);
            }
            float sa = ((da.x + da.y) + (da.z + da.w)) * 0.125f;
            float sb = ((db.x + db.y) + (db.z + db.w)) * 0.125f;
            if (!sMask[k]) { sa = EPS_; sb = EPS_; }
            pA[kk] = sa; pB[kk] = sb;
            mxA = fmaxf(mxA, sa); mxB = fmaxf(mxB, sb);
        }
        // reduce max over the 8-lane query group
#pragma unroll
        for (int off = 1; off < 8; off <<= 1) {
            mxA = fmaxf(mxA, __shfl_xor(mxA, off));
            mxB = fmaxf(mxB, __shfl_xor(mxB, off));
        }
        const float mnA = fmaxf(mA, mxA), mnB = fmaxf(mB, mxB);
        const float scA = __expf(mA - mnA), scB = __expf(mB - mnB);
        float lsA = 0.f, lsB = 0.f;
#pragma unroll
        for (int kk = 0; kk < 8; ++kk) {
            pA[kk] = __expf(pA[kk] - mnA); lsA += pA[kk];
            pB[kk] = __expf(pB[kk] - mnB); lsB += pB[kk];
        }
#pragma unroll
        for (int off = 1; off < 8; off <<= 1) {
            lsA += __shfl_xor(lsA, off);
            lsB += __shfl_xor(lsB, off);
        }
        lA = lA * scA + lsA; lB = lB * scB + lsB;
        mA = mnA; mB = mnB;
        // P (with cutoff) to LDS — written & read by the same wave only
#pragma unroll
        for (int kk = 0; kk < 8; ++kk) {
            const int k = kk * 8 + i8;
            const float c = sCut[k];
            sP[ql][k]      = pA[kk] * c;
            sP[ql + 32][k] = pB[kk] * c;
        }
#pragma unroll
        for (int j = 0; j < 8; ++j) { accA[j] *= scA; accB[j] *= scB; }
        // PV: acc[d] += sum_k P[q][k] * V[k][d]
#pragma unroll
        for (int k = 0; k < 64; ++k) {
            const float pa = sP[ql][k], pb = sP[ql + 32][k];
            const float4 v0 = *reinterpret_cast<const float4*>(&sV[k][i8 * 8]);
            const float4 v1 = *reinterpret_cast<const float4*>(&sV[k][i8 * 8 + 4]);
            accA[0] = fmaf(pa, v0.x, accA[0]); accA[1] = fmaf(pa, v0.y, accA[1]);
            accA[2] = fmaf(pa, v0.z, accA[2]); accA[3] = fmaf(pa, v0.w, accA[3]);
            accA[4] = fmaf(pa, v1.x, accA[4]); accA[5] = fmaf(pa, v1.y, accA[5]);
            accA[6] = fmaf(pa, v1.z, accA[6]); accA[7] = fmaf(pa, v1.w, accA[7]);
            accB[0] = fmaf(pb, v0.x, accB[0]); accB[1] = fmaf(pb, v0.y, accB[1]);
            accB[2] = fmaf(pb, v0.z, accB[2]); accB[3] = fmaf(pb, v0.w, accB[3]);
            accB[4] = fmaf(pb, v1.x, accB[4]); accB[5] = fmaf(pb, v1.y, accB[5]);
            accB[6] = fmaf(pb, v1.z, accB[6]); accB[7] = fmaf(pb, v1.w, accB[7]);
        }
    }

    const float iA = 1.f / lA, iB = 1.f / lB;
    float* oA = att + ((size_t)(b * S_ + q0 + ql)) * D_ + h * DH_ + i8 * 8;
    float* oB = att + ((size_t)(b * S_ + q0 + ql + 32)) * D_ + h * DH_ + i8 * 8;
    *reinterpret_cast<float4*>(oA) =
        make_float4(accA[0] * iA, accA[1] * iA, accA[2] * iA, accA[3] * iA);
    *reinterpret_cast<float4*>(oA + 4) =
        make_float4(accA[4] * iA, accA[5] * iA, accA[6] * iA, accA[7] * iA);
    *reinterpret_cast<float4*>(oB) =
        make_float4(accB[0] * iB, accB[1] * iB, accB[2] * iB, accB[3] * iB);
    *reinterpret_cast<float4*>(oB + 4) =
        make_float4(accB[4] * iB, accB[5] * iB, accB[6] * iB, accB[7] * iB);
}

// ---------------------------------------------------------------------------
// Kernel B: out[8192,512] = att[8192,512] @ W[512,512], fp32 LDS-tiled GEMM.
// 64x64 output tile per block, 256 threads, each thread 4x4 outputs.
// ---------------------------------------------------------------------------
__global__ __launch_bounds__(256) void proj_fp32_kernel(
    const float* __restrict__ A, const float* __restrict__ W,
    float* __restrict__ out)
{
    const int M = B_ * S_;              // 8192
    const int rt = blockIdx.x % (M / 64);
    const int ct = blockIdx.x / (M / 64);
    const int r0 = rt * 64, c0 = ct * 64;

    __shared__ float sA[16][68];        // [k][r] (transposed)
    __shared__ float sB[16][68];        // [k][c]

    const int tid = threadIdx.x;
    const int ty = tid >> 4;            // 0..15 -> rows ty*4..ty*4+3
    const int tx = tid & 15;            // 0..15 -> cols tx*4..tx*4+3

    float acc[4][4];
#pragma unroll
    for (int i = 0; i < 4; ++i)
#pragma unroll
        for (int j = 0; j < 4; ++j) acc[i][j] = 0.f;

    for (int k0 = 0; k0 < D_; k0 += 16) {
        __syncthreads();
        {
            const int r  = tid >> 2;            // 0..63
            const int k4 = (tid & 3) * 4;       // 0,4,8,12
            const float4 a4 = *reinterpret_cast<const float4*>(
                A + (size_t)(r0 + r) * D_ + k0 + k4);
            sA[k4 + 0][r] = a4.x; sA[k4 + 1][r] = a4.y;
            sA[k4 + 2][r] = a4.z; sA[k4 + 3][r] = a4.w;
            const int kb = tid >> 4;            // 0..15
            const int c4 = (tid & 15) * 4;
            *reinterpret_cast<float4*>(&sB[kb][c4]) =
                *reinterpret_cast<const float4*>(W + (size_t)(k0 + kb) * D_ + c0 + c4);
        }
        __syncthreads();
#pragma unroll
        for (int k = 0; k < 16; ++k) {
            const float4 a = *reinterpret_cast<const float4*>(&sA[k][ty * 4]);
            const float4 bv = *reinterpret_cast<const float4*>(&sB[k][tx * 4]);
            acc[0][0] = fmaf(a.x, bv.x, acc[0][0]); acc[0][1] = fmaf(a.x, bv.y, acc[0][1]);
            acc[0][2] = fmaf(a.x, bv.z, acc[0][2]); acc[0][3] = fmaf(a.x, bv.w, acc[0][3]);
            acc[1][0] = fmaf(a.y, bv.x, acc[1][0]); acc[1][1] = fmaf(a.y, bv.y, acc[1][1]);
            acc[1][2] = fmaf(a.y, bv.z, acc[1][2]); acc[1][3] = fmaf(a.y, bv.w, acc[1][3]);
            acc[2][0] = fmaf(a.z, bv.x, acc[2][0]); acc[2][1] = fmaf(a.z, bv.y, acc[2][1]);
            acc[2][2] = fmaf(a.z, bv.z, acc[2][2]); acc[2][3] = fmaf(a.z, bv.w, acc[2][3]);
            acc[3][0] = fmaf(a.w, bv.x, acc[3][0]); acc[3][1] = fmaf(a.w, bv.y, acc[3][1]);
            acc[3][2] = fmaf(a.w, bv.z, acc[3][2]); acc[3][3] = fmaf(a.w, bv.w, acc[3][3]);
        }
    }
#pragma unroll
    for (int j = 0; j < 4; ++j) {
        *reinterpret_cast<float4*>(out + (size_t)(r0 + ty * 4 + j) * D_ + c0 + tx * 4) =
            make_float4(acc[j][0], acc[j][1], acc[j][2], acc[j][3]);
    }
}

extern "C" void kernel_launch(void* const* d_in, const int* in_sizes, int n_in,
                              void* d_out, int out_size, void* d_ws, size_t ws_size,
                              hipStream_t stream) {
    const float* q    = (const float*)d_in[0];
    const float* k    = (const float*)d_in[1];
    const float* v    = (const float*)d_in[2];
    const int*   mask = (const int*)d_in[3];
    const float* cut  = (const float*)d_in[4];
    const float* W    = (const float*)d_in[5];
    float* out = (float*)d_out;
    float* att = (float*)d_ws;          // 4*2048*512 fp32 = 16 MB scratch

    attn_fp32_kernel<<<B_ * H_ * (S_ / 64), 256, 0, stream>>>(q, k, v, mask, cut, att);
    proj_fp32_kernel<<<(B_ * S_ / 64) * (D_ / 64), 256, 0, stream>>>(att, W, out);
}

// Round 2
// 142.234 us; speedup vs baseline: 11.5732x; 11.5732x over previous
//
#include <hip/hip_runtime.h>
#include <hip/hip_bf16.h>
#include <stdint.h>

#define B_ 4
#define S_ 2048
#define D_ 512
#define H_ 8
#define EPS_ -50000.0f

typedef __attribute__((ext_vector_type(4))) float f32x4;
typedef __attribute__((ext_vector_type(8))) short s16x8;

__device__ __forceinline__ unsigned short f2bf(float x) {
  union { float f; unsigned u; } v; v.f = x;
  unsigned r = v.u + 0x7FFFu + ((v.u >> 16) & 1u);
  return (unsigned short)(r >> 16);
}

__device__ __forceinline__ void gload16(const void* g, void* lds) {
  __builtin_amdgcn_global_load_lds(
      (const __attribute__((address_space(1))) void*)g,
      (__attribute__((address_space(3))) void*)lds, 16, 0, 0);
}

// ---------------------------------------------------------------------------
// conv_kv: Kbf[bh][s][dh] = bf16(K), Vt[bh][dh][s] = bf16(V * cutoff[s])
// grid (S/64, B*H), 256 threads
// ---------------------------------------------------------------------------
__global__ __launch_bounds__(256) void conv_kv_kernel(
    const float* __restrict__ km, const float* __restrict__ vm,
    const float* __restrict__ cut,
    unsigned short* __restrict__ Kbf, unsigned short* __restrict__ Vt)
{
  const int st = blockIdx.x, bh = blockIdx.y;
  const int b = bh >> 3, h = bh & 7;
  const int s0 = st * 64;
  __shared__ unsigned short sT[64][68];
  const int tid = threadIdx.x;
#pragma unroll
  for (int j = 0; j < 4; ++j) {
    const int li = tid + j * 256;
    const int r  = li >> 4;
    const int c4 = (li & 15) * 4;
    const size_t g = ((size_t)(b * S_ + s0 + r)) * D_ + h * 64 + c4;
    const float4 kv = *(const float4*)(km + g);
    const float4 vv = *(const float4*)(vm + g);
    const float cu = cut[(size_t)b * S_ + s0 + r];
    *(ushort4*)(Kbf + ((size_t)(bh * S_ + s0 + r)) * 64 + c4) =
        make_ushort4(f2bf(kv.x), f2bf(kv.y), f2bf(kv.z), f2bf(kv.w));
    sT[r][c4 + 0] = f2bf(vv.x * cu);
    sT[r][c4 + 1] = f2bf(vv.y * cu);
    sT[r][c4 + 2] = f2bf(vv.z * cu);
    sT[r][c4 + 3] = f2bf(vv.w * cu);
  }
  __syncthreads();
#pragma unroll
  for (int j = 0; j < 4; ++j) {
    const int li = tid + j * 256;
    const int dh = li >> 4;
    const int s4 = (li & 15) * 4;
    *(ushort4*)(Vt + ((size_t)(bh * 64 + dh)) * S_ + s0 + s4) =
        make_ushort4(sT[s4 + 0][dh], sT[s4 + 1][dh], sT[s4 + 2][dh], sT[s4 + 3][dh]);
  }
}

// ---------------------------------------------------------------------------
// conv_w: Wt[n][k] = bf16(W[k][n]).  grid (8, 8), 256 threads
// ---------------------------------------------------------------------------
__global__ __launch_bounds__(256) void conv_w_kernel(
    const float* __restrict__ W, unsigned short* __restrict__ Wt)
{
  const int k0 = blockIdx.x * 64, n0 = blockIdx.y * 64;
  __shared__ unsigned short sT[64][68];
  const int tid = threadIdx.x;
#pragma unroll
  for (int j = 0; j < 4; ++j) {
    const int li = tid + j * 256;
    const int r  = li >> 4;            // k
    const int c4 = (li & 15) * 4;      // n
    const float4 wv = *(const float4*)(W + (size_t)(k0 + r) * 512 + n0 + c4);
    sT[r][c4 + 0] = f2bf(wv.x);
    sT[r][c4 + 1] = f2bf(wv.y);
    sT[r][c4 + 2] = f2bf(wv.z);
    sT[r][c4 + 3] = f2bf(wv.w);
  }
  __syncthreads();
#pragma unroll
  for (int j = 0; j < 4; ++j) {
    const int li = tid + j * 256;
    const int n  = li >> 4;
    const int k4 = (li & 15) * 4;
    *(ushort4*)(Wt + (size_t)(n0 + n) * 512 + k0 + k4) =
        make_ushort4(sT[k4 + 0][n], sT[k4 + 1][n], sT[k4 + 2][n], sT[k4 + 3][n]);
  }
}

// ---------------------------------------------------------------------------
// attn: flash attention, bf16 MFMA 16x16x32.
// grid (S/128, B*H), 256 threads = 4 waves, each wave owns 32 query rows.
// KV tile = 64 keys. LDS tiles XOR-swizzled (byte ^= (row&7)<<4) via
// pre-swizzled per-lane global sources into global_load_lds (linear dest).
// ---------------------------------------------------------------------------
__global__ __launch_bounds__(256) void attn_mfma_kernel(
    const float* __restrict__ qv, const unsigned short* __restrict__ Kbf,
    const unsigned short* __restrict__ Vt, const int* __restrict__ mask,
    unsigned short* __restrict__ attb)
{
  __shared__ unsigned short sK[64 * 64];     // [key][dh] swizzled, 8 KB
  __shared__ unsigned short sV[64 * 64];     // [dh][key] swizzled, 8 KB
  __shared__ unsigned short sP[4][32 * 64];  // per-wave [q][key] swizzled, 16 KB
  __shared__ int sMask[64];

  const int qt = blockIdx.x, bh = blockIdx.y;
  const int b = bh >> 3, h = bh & 7;
  const int tid = threadIdx.x, w = tid >> 6, l = tid & 63;
  const int l15 = l & 15, l4 = l >> 4;
  unsigned short* sPw = sP[w];

  // Q fragments (1/sqrt(dh)=0.125 folded in), converted fp32->bf16 in-kernel
  s16x8 qf[2][2];
#pragma unroll
  for (int mr = 0; mr < 2; ++mr)
#pragma unroll
    for (int ks = 0; ks < 2; ++ks) {
      const int q = qt * 128 + w * 32 + mr * 16 + l15;
      const float* qp = qv + ((size_t)(b * S_ + q)) * D_ + h * 64 + ks * 32 + l4 * 8;
      const float4 a0 = *(const float4*)qp;
      const float4 a1 = *(const float4*)(qp + 4);
      s16x8 f;
      f[0] = (short)f2bf(a0.x * 0.125f); f[1] = (short)f2bf(a0.y * 0.125f);
      f[2] = (short)f2bf(a0.z * 0.125f); f[3] = (short)f2bf(a0.w * 0.125f);
      f[4] = (short)f2bf(a1.x * 0.125f); f[5] = (short)f2bf(a1.y * 0.125f);
      f[6] = (short)f2bf(a1.z * 0.125f); f[7] = (short)f2bf(a1.w * 0.125f);
      qf[mr][ks] = f;
    }

  f32x4 o[2][4];
  float mrow[2][4], lrow[2][4];
#pragma unroll
  for (int mr = 0; mr < 2; ++mr)
#pragma unroll
    for (int nb = 0; nb < 4; ++nb) o[mr][nb] = (f32x4){0.f, 0.f, 0.f, 0.f};
#pragma unroll
  for (int mr = 0; mr < 2; ++mr)
#pragma unroll
    for (int r = 0; r < 4; ++r) { mrow[mr][r] = -INFINITY; lrow[mr][r] = 0.f; }

  const int swl = ((l & 7) ^ (l >> 3)) * 16;  // pre-swizzled source byte offset
  const int r8  = l >> 3;                     // row within an 8-row chunk

  for (int kt = 0; kt < S_ / 64; ++kt) {
    const int k0 = kt * 64;
    __syncthreads();
#pragma unroll
    for (int c = 0; c < 2; ++c) {
      const int chunk = w * 2 + c;
      const int r = chunk * 8 + r8;
      gload16((const char*)(Kbf + ((size_t)bh * S_ + k0 + r) * 64) + swl,
              (char*)sK + chunk * 1024);
      gload16((const char*)(Vt + ((size_t)(bh * 64 + r)) * S_ + k0) + swl,
              (char*)sV + chunk * 1024);
    }
    if (tid < 64) sMask[tid] = mask[(size_t)b * S_ + k0 + tid];
    __syncthreads();

    // K fragments (B-operand): lane holds K[key=l&15+16*kb][k=(l>>4)*8+j]
    s16x8 kf[4][2];
#pragma unroll
    for (int kb = 0; kb < 4; ++kb) {
      const int row = kb * 16 + l15;
      const int sz = (row & 7) << 4;
#pragma unroll
      for (int ks = 0; ks < 2; ++ks)
        kf[kb][ks] = *(const s16x8*)((const char*)sK + row * 128 +
                                     ((ks * 64 + l4 * 16) ^ sz));
    }
    int mv[4];
#pragma unroll
    for (int kb = 0; kb < 4; ++kb) mv[kb] = sMask[kb * 16 + l15];

    // QK^T
    f32x4 s_[2][4];
#pragma unroll
    for (int mr = 0; mr < 2; ++mr)
#pragma unroll
      for (int kb = 0; kb < 4; ++kb) {
        f32x4 acc = (f32x4){0.f, 0.f, 0.f, 0.f};
        acc = __builtin_amdgcn_mfma_f32_16x16x32_bf16(qf[mr][0], kf[kb][0], acc, 0, 0, 0);
        acc = __builtin_amdgcn_mfma_f32_16x16x32_bf16(qf[mr][1], kf[kb][1], acc, 0, 0, 0);
        if (!mv[kb]) acc = (f32x4){EPS_, EPS_, EPS_, EPS_};
        s_[mr][kb] = acc;
      }

    // online softmax (per 16-lane group; rows q = mr*16 + l4*4 + r)
    float pm[2][4], sc_[2][4], ps[2][4];
#pragma unroll
    for (int mr = 0; mr < 2; ++mr)
#pragma unroll
      for (int r = 0; r < 4; ++r)
        pm[mr][r] = fmaxf(fmaxf(s_[mr][0][r], s_[mr][1][r]),
                          fmaxf(s_[mr][2][r], s_[mr][3][r]));
#pragma unroll
    for (int off = 1; off < 16; off <<= 1)
#pragma unroll
      for (int mr = 0; mr < 2; ++mr)
#pragma unroll
        for (int r = 0; r < 4; ++r)
          pm[mr][r] = fmaxf(pm[mr][r], __shfl_xor(pm[mr][r], off));
#pragma unroll
    for (int mr = 0; mr < 2; ++mr)
#pragma unroll
      for (int r = 0; r < 4; ++r) {
        const float mn = fmaxf(mrow[mr][r], pm[mr][r]);
        sc_[mr][r] = __expf(mrow[mr][r] - mn);
        mrow[mr][r] = mn;
        ps[mr][r] = 0.f;
      }
#pragma unroll
    for (int mr = 0; mr < 2; ++mr)
#pragma unroll
      for (int kb = 0; kb < 4; ++kb) {
        const int key = kb * 16 + l15;
#pragma unroll
        for (int r = 0; r < 4; ++r) {
          const float p = __expf(s_[mr][kb][r] - mrow[mr][r]);
          ps[mr][r] += p;
          const int q = mr * 16 + l4 * 4 + r;
          *(unsigned short*)((char*)sPw + q * 128 + ((key * 2) ^ ((q & 7) << 4))) = f2bf(p);
        }
      }
#pragma unroll
    for (int off = 1; off < 16; off <<= 1)
#pragma unroll
      for (int mr = 0; mr < 2; ++mr)
#pragma unroll
        for (int r = 0; r < 4; ++r)
          ps[mr][r] += __shfl_xor(ps[mr][r], off);
#pragma unroll
    for (int mr = 0; mr < 2; ++mr)
#pragma unroll
      for (int r = 0; r < 4; ++r)
        lrow[mr][r] = lrow[mr][r] * sc_[mr][r] + ps[mr][r];

    asm volatile("" ::: "memory");  // keep P stores before PV fragment reads

    // rescale accumulator
#pragma unroll
    for (int mr = 0; mr < 2; ++mr)
#pragma unroll
      for (int nb = 0; nb < 4; ++nb)
#pragma unroll
        for (int r = 0; r < 4; ++r) o[mr][nb][r] *= sc_[mr][r];

    // PV: V fragments (B), P fragments (A)
    s16x8 vb[4][2];
#pragma unroll
    for (int nb = 0; nb < 4; ++nb) {
      const int row = nb * 16 + l15;
      const int sz = (row & 7) << 4;
#pragma unroll
      for (int ks = 0; ks < 2; ++ks)
        vb[nb][ks] = *(const s16x8*)((const char*)sV + row * 128 +
                                     ((ks * 64 + l4 * 16) ^ sz));
    }
#pragma unroll
    for (int mr = 0; mr < 2; ++mr) {
      const int row = mr * 16 + l15;
      const int sz = (row & 7) << 4;
      const s16x8 pa0 = *(const s16x8*)((const char*)sPw + row * 128 + ((l4 * 16) ^ sz));
      const s16x8 pa1 = *(const s16x8*)((const char*)sPw + row * 128 + ((64 + l4 * 16) ^ sz));
#pragma unroll
      for (int nb = 0; nb < 4; ++nb) {
        o[mr][nb] = __builtin_amdgcn_mfma_f32_16x16x32_bf16(pa0, vb[nb][0], o[mr][nb], 0, 0, 0);
        o[mr][nb] = __builtin_amdgcn_mfma_f32_16x16x32_bf16(pa1, vb[nb][1], o[mr][nb], 0, 0, 0);
      }
    }
  }

  // epilogue: normalize and store bf16 att
  float inv[2][4];
#pragma unroll
  for (int mr = 0; mr < 2; ++mr)
#pragma unroll
    for (int r = 0; r < 4; ++r) inv[mr][r] = 1.f / lrow[mr][r];
#pragma unroll
  for (int mr = 0; mr < 2; ++mr)
#pragma unroll
    for (int nb = 0; nb < 4; ++nb)
#pragma unroll
      for (int r = 0; r < 4; ++r) {
        const int q = qt * 128 + w * 32 + mr * 16 + l4 * 4 + r;
        const int dh = nb * 16 + l15;
        attb[((size_t)(b * S_ + q)) * D_ + h * 64 + dh] = f2bf(o[mr][nb][r] * inv[mr][r]);
      }
}

// ---------------------------------------------------------------------------
// proj: out[8192,512] = attb(bf16) @ W via Wt[n][k], MFMA, 128x128 tiles.
// grid (64, 4), 256 threads = 4 waves (2x2), each wave 64x64.
// ---------------------------------------------------------------------------
__global__ __launch_bounds__(256) void proj_mfma_kernel(
    const unsigned short* __restrict__ A, const unsigned short* __restrict__ Wt,
    float* __restrict__ out)
{
  __shared__ unsigned short sA[128 * 64];  // [m][k] swizzled, 16 KB
  __shared__ unsigned short sB[128 * 64];  // [n][k] swizzled, 16 KB
  const int m0 = blockIdx.x * 128, n0 = blockIdx.y * 128;
  const int tid = threadIdx.x, w = tid >> 6, l = tid & 63;
  const int l15 = l & 15, l4 = l >> 4;
  const int wm = (w >> 1) * 64, wn = (w & 1) * 64;
  const int swl = ((l & 7) ^ (l >> 3)) * 16;
  const int r8 = l >> 3;

  f32x4 acc[4][4];
#pragma unroll
  for (int i = 0; i < 4; ++i)
#pragma unroll
    for (int j = 0; j < 4; ++j) acc[i][j] = (f32x4){0.f, 0.f, 0.f, 0.f};

  for (int kt = 0; kt < 8; ++kt) {
    const int k0 = kt * 64;
    __syncthreads();
#pragma unroll
    for (int c = 0; c < 4; ++c) {
      const int chunk = w * 4 + c;
      const int r = chunk * 8 + r8;
      gload16((const char*)(A + ((size_t)(m0 + r)) * 512 + k0) + swl,
              (char*)sA + chunk * 1024);
      gload16((const char*)(Wt + ((size_t)(n0 + r)) * 512 + k0) + swl,
              (char*)sB + chunk * 1024);
    }
    __syncthreads();
#pragma unroll
    for (int ks = 0; ks < 2; ++ks) {
      s16x8 af[4], bf_[4];
#pragma unroll
      for (int mb = 0; mb < 4; ++mb) {
        const int row = wm + mb * 16 + l15;
        const int sz = (row & 7) << 4;
        af[mb] = *(const s16x8*)((const char*)sA + row * 128 + ((ks * 64 + l4 * 16) ^ sz));
      }
#pragma unroll
      for (int nb = 0; nb < 4; ++nb) {
        const int row = wn + nb * 16 + l15;
        const int sz = (row & 7) << 4;
        bf_[nb] = *(const s16x8*)((const char*)sB + row * 128 + ((ks * 64 + l4 * 16) ^ sz));
      }
#pragma unroll
      for (int mb = 0; mb < 4; ++mb)
#pragma unroll
        for (int nb = 0; nb < 4; ++nb)
          acc[mb][nb] = __builtin_amdgcn_mfma_f32_16x16x32_bf16(af[mb], bf_[nb], acc[mb][nb], 0, 0, 0);
    }
  }
#pragma unroll
  for (int mb = 0; mb < 4; ++mb)
#pragma unroll
    for (int nb = 0; nb < 4; ++nb)
#pragma unroll
      for (int r = 0; r < 4; ++r)
        out[(size_t)(m0 + wm + mb * 16 + l4 * 4 + r) * 512 + n0 + wn + nb * 16 + l15] =
            acc[mb][nb][r];
}

extern "C" void kernel_launch(void* const* d_in, const int* in_sizes, int n_in,
                              void* d_out, int out_size, void* d_ws, size_t ws_size,
                              hipStream_t stream) {
  const float* q    = (const float*)d_in[0];
  const float* k    = (const float*)d_in[1];
  const float* v    = (const float*)d_in[2];
  const int*   mask = (const int*)d_in[3];
  const float* cut  = (const float*)d_in[4];
  const float* W    = (const float*)d_in[5];
  float* out = (float*)d_out;

  char* ws = (char*)d_ws;
  unsigned short* Kbf  = (unsigned short*)(ws);                    // 8 MB
  unsigned short* Vt   = (unsigned short*)(ws + (8u << 20));       // 8 MB
  unsigned short* attb = (unsigned short*)(ws + (16u << 20));      // 8 MB
  unsigned short* Wt   = (unsigned short*)(ws + (24u << 20));      // 0.5 MB

  conv_kv_kernel<<<dim3(S_ / 64, B_ * H_), 256, 0, stream>>>(k, v, cut, Kbf, Vt);
  conv_w_kernel<<<dim3(8, 8), 256, 0, stream>>>(W, Wt);
  attn_mfma_kernel<<<dim3(S_ / 128, B_ * H_), 256, 0, stream>>>(q, Kbf, Vt, mask, attb);
  proj_mfma_kernel<<<dim3(64, 4), 256, 0, stream>>>(attb, Wt, out);
}

// Round 3
// 81.925 us; speedup vs baseline: 20.0930x; 1.7362x over previous
//
#include <hip/hip_runtime.h>
#include <hip/hip_bf16.h>
#include <stdint.h>

#define B_ 4
#define S_ 2048
#define D_ 512
#define H_ 8

typedef __attribute__((ext_vector_type(4))) float f32x4;
typedef __attribute__((ext_vector_type(16))) float f32x16;
typedef __attribute__((ext_vector_type(8))) short s16x8;

__device__ __forceinline__ unsigned short f2bf(float x) {
  union { float f; unsigned u; } v; v.f = x;
  unsigned r = v.u + 0x7FFFu + ((v.u >> 16) & 1u);
  return (unsigned short)(r >> 16);
}

__device__ __forceinline__ unsigned cvtpk_bf16(float lo, float hi) {
  unsigned r;
  asm("v_cvt_pk_bf16_f32 %0, %1, %2" : "=v"(r) : "v"(lo), "v"(hi));
  return r;
}

// v_permlane32_swap_b32: a <- {a.lo, b.lo}, b <- {a.hi, b.hi}
__device__ __forceinline__ void plswap(unsigned &a, unsigned &b) {
  asm("v_permlane32_swap_b32 %0, %1" : "+v"(a), "+v"(b));
}

__device__ __forceinline__ void gload16(const void* g, void* lds) {
  __builtin_amdgcn_global_load_lds(
      (const __attribute__((address_space(1))) void*)g,
      (__attribute__((address_space(3))) void*)lds, 16, 0, 0);
}

// ---------------------------------------------------------------------------
// conv_kv: Kbf[bh][s][dh] = bf16(K); Vt[bh][dh][s] = bf16(V * cutoff * mask);
// fmg[b][s] = bf16(mask ? 1 : 0).  grid (S/64, B*H), 256 threads.
// ---------------------------------------------------------------------------
__global__ __launch_bounds__(256) void conv_kv_kernel(
    const float* __restrict__ km, const float* __restrict__ vm,
    const float* __restrict__ cut, const int* __restrict__ mask,
    unsigned short* __restrict__ Kbf, unsigned short* __restrict__ Vt,
    unsigned short* __restrict__ fmg)
{
  const int st = blockIdx.x, bh = blockIdx.y;
  const int b = bh >> 3, h = bh & 7;
  const int s0 = st * 64;
  __shared__ unsigned short sT[64][68];
  const int tid = threadIdx.x;
#pragma unroll
  for (int j = 0; j < 4; ++j) {
    const int li = tid + j * 256;
    const int r  = li >> 4;
    const int c4 = (li & 15) * 4;
    const size_t g = ((size_t)(b * S_ + s0 + r)) * D_ + h * 64 + c4;
    const float4 kv = *(const float4*)(km + g);
    const float4 vv = *(const float4*)(vm + g);
    const int mk = mask[(size_t)b * S_ + s0 + r];
    const float f = mk ? cut[(size_t)b * S_ + s0 + r] : 0.f;
    *(ushort4*)(Kbf + ((size_t)(bh * S_ + s0 + r)) * 64 + c4) =
        make_ushort4(f2bf(kv.x), f2bf(kv.y), f2bf(kv.z), f2bf(kv.w));
    sT[r][c4 + 0] = f2bf(vv.x * f);
    sT[r][c4 + 1] = f2bf(vv.y * f);
    sT[r][c4 + 2] = f2bf(vv.z * f);
    sT[r][c4 + 3] = f2bf(vv.w * f);
    if (h == 0 && c4 == 0)
      fmg[(size_t)b * S_ + s0 + r] = mk ? (unsigned short)0x3F80 : (unsigned short)0;
  }
  __syncthreads();
#pragma unroll
  for (int j = 0; j < 4; ++j) {
    const int li = tid + j * 256;
    const int dh = li >> 4;
    const int s4 = (li & 15) * 4;
    *(ushort4*)(Vt + ((size_t)(bh * 64 + dh)) * S_ + s0 + s4) =
        make_ushort4(sT[s4 + 0][dh], sT[s4 + 1][dh], sT[s4 + 2][dh], sT[s4 + 3][dh]);
  }
}

// ---------------------------------------------------------------------------
// conv_w: Wt[n][k] = bf16(W[k][n]).  grid (8, 8), 256 threads
// ---------------------------------------------------------------------------
__global__ __launch_bounds__(256) void conv_w_kernel(
    const float* __restrict__ W, unsigned short* __restrict__ Wt)
{
  const int k0 = blockIdx.x * 64, n0 = blockIdx.y * 64;
  __shared__ unsigned short sT[64][68];
  const int tid = threadIdx.x;
#pragma unroll
  for (int j = 0; j < 4; ++j) {
    const int li = tid + j * 256;
    const int r  = li >> 4;
    const int c4 = (li & 15) * 4;
    const float4 wv = *(const float4*)(W + (size_t)(k0 + r) * 512 + n0 + c4);
    sT[r][c4 + 0] = f2bf(wv.x);
    sT[r][c4 + 1] = f2bf(wv.y);
    sT[r][c4 + 2] = f2bf(wv.z);
    sT[r][c4 + 3] = f2bf(wv.w);
  }
  __syncthreads();
#pragma unroll
  for (int j = 0; j < 4; ++j) {
    const int li = tid + j * 256;
    const int n  = li >> 4;
    const int k4 = (li & 15) * 4;
    *(ushort4*)(Wt + (size_t)(n0 + n) * 512 + k0 + k4) =
        make_ushort4(sT[k4 + 0][n], sT[k4 + 1][n], sT[k4 + 2][n], sT[k4 + 3][n]);
  }
}

// ---------------------------------------------------------------------------
// attn: swapped-QK^T flash attention, 32x32x16 bf16 MFMA, no max tracking.
// grid (S/128, B*H), 256 threads = 4 waves, each wave 32 query rows.
// S^T = K·Q^T (lane holds one query col), p = exp(s) unnormalized,
// P->A-frag via cvt_pk + permlane32_swap, l via mfma with fmask column.
// ---------------------------------------------------------------------------
__global__ __launch_bounds__(256) void attn_mfma_kernel(
    const float* __restrict__ qv, const unsigned short* __restrict__ Kbf,
    const unsigned short* __restrict__ Vt, const unsigned short* __restrict__ fmg,
    unsigned short* __restrict__ attb)
{
  __shared__ unsigned short sK[2][64 * 64];   // [key][dh] swizzled, 8 KB each
  __shared__ unsigned short sV[2][64 * 64];   // [dh][key] swizzled, 8 KB each
  __shared__ unsigned short sF[2][64];        // fmask bf16

  const int qt = blockIdx.x, bh = blockIdx.y;
  const int b = bh >> 3, h = bh & 7;
  const int tid = threadIdx.x, w = tid >> 6, l = tid & 63;
  const int l31 = l & 31, hi = l >> 5;
  const int q0 = qt * 128 + w * 32;

  // Q B-fragments: lane holds Q[q0+l31][h*64 + kc*16 + hi*8 + j] * 0.125
  s16x8 qf[4];
  {
    const float* qp = qv + ((size_t)(b * S_ + q0 + l31)) * D_ + h * 64 + hi * 8;
#pragma unroll
    for (int kc = 0; kc < 4; ++kc) {
      const float4 a0 = *(const float4*)(qp + kc * 16);
      const float4 a1 = *(const float4*)(qp + kc * 16 + 4);
      union { unsigned u[4]; s16x8 v; } t;
      t.u[0] = cvtpk_bf16(a0.x * 0.125f, a0.y * 0.125f);
      t.u[1] = cvtpk_bf16(a0.z * 0.125f, a0.w * 0.125f);
      t.u[2] = cvtpk_bf16(a1.x * 0.125f, a1.y * 0.125f);
      t.u[3] = cvtpk_bf16(a1.z * 0.125f, a1.w * 0.125f);
      qf[kc] = t.v;
    }
  }

  f32x16 o0, o1, lacc;
#pragma unroll
  for (int r = 0; r < 16; ++r) { o0[r] = 0.f; o1[r] = 0.f; lacc[r] = 0.f; }

  const int swl = ((l & 7) ^ (l >> 3)) * 16;  // pre-swizzled source byte offset
  const int r8  = l >> 3;

  auto STAGE = [&](int bufi, int kt) {
    const int k0 = kt * 64;
#pragma unroll
    for (int c = 0; c < 2; ++c) {
      const int chunk = w * 2 + c;
      const int r = chunk * 8 + r8;
      gload16((const char*)(Kbf + ((size_t)bh * S_ + k0 + r) * 64) + swl,
              (char*)sK[bufi] + chunk * 1024);
      gload16((const char*)(Vt + ((size_t)(bh * 64 + r)) * S_ + k0) + swl,
              (char*)sV[bufi] + chunk * 1024);
    }
    if (tid < 8)
      gload16((const char*)(fmg + (size_t)b * S_ + k0) + tid * 16, (char*)sF[bufi]);
  };

  STAGE(0, 0);
  __syncthreads();

  int buf = 0;
  for (int kt = 0; kt < S_ / 64; ++kt) {
    if (kt + 1 < S_ / 64) STAGE(buf ^ 1, kt + 1);

    const char* pK = (const char*)sK[buf];
    const char* pV = (const char*)sV[buf];
    const char* pF = (const char*)sF[buf];

    // QK^T swapped: sacc[kb2], D[key][q]
    f32x16 sacc0, sacc1;
#pragma unroll
    for (int r = 0; r < 16; ++r) { sacc0[r] = 0.f; sacc1[r] = 0.f; }
    __builtin_amdgcn_s_setprio(1);
#pragma unroll
    for (int kc = 0; kc < 4; ++kc) {
      const int cb = kc * 32 + hi * 16;
      const int row0 = l31, row1 = 32 + l31;
      const s16x8 kf0 = *(const s16x8*)(pK + row0 * 128 + (cb ^ ((row0 & 7) << 4)));
      const s16x8 kf1 = *(const s16x8*)(pK + row1 * 128 + (cb ^ ((row1 & 7) << 4)));
      sacc0 = __builtin_amdgcn_mfma_f32_32x32x16_bf16(kf0, qf[kc], sacc0, 0, 0, 0);
      sacc1 = __builtin_amdgcn_mfma_f32_32x32x16_bf16(kf1, qf[kc], sacc1, 0, 0, 0);
    }
    __builtin_amdgcn_s_setprio(0);

    // p = exp(s)  (no max subtraction; scores bounded, see analysis)
    float p0[16], p1[16];
#pragma unroll
    for (int r = 0; r < 16; ++r) { p0[r] = __expf(sacc0[r]); p1[r] = __expf(sacc1[r]); }

    // PV + lsum, per 16-key slice ks2
    __builtin_amdgcn_s_setprio(1);
#pragma unroll
    for (int ks2 = 0; ks2 < 4; ++ks2) {
      const float* ps = (ks2 < 2) ? p0 : p1;
      const int rb = (ks2 & 1) * 8;
      unsigned a0 = cvtpk_bf16(ps[rb + 0], ps[rb + 1]);
      unsigned a1 = cvtpk_bf16(ps[rb + 2], ps[rb + 3]);
      unsigned b0 = cvtpk_bf16(ps[rb + 4], ps[rb + 5]);
      unsigned b1 = cvtpk_bf16(ps[rb + 6], ps[rb + 7]);
      plswap(a0, b0);
      plswap(a1, b1);
      union { unsigned u[4]; s16x8 v; } pa;
      pa.u[0] = a0; pa.u[1] = a1; pa.u[2] = b0; pa.u[3] = b1;

      const int cb = ks2 * 32 + hi * 16;
      const int rv0 = l31, rv1 = 32 + l31;
      const s16x8 vb0 = *(const s16x8*)(pV + rv0 * 128 + (cb ^ ((rv0 & 7) << 4)));
      const s16x8 vb1 = *(const s16x8*)(pV + rv1 * 128 + (cb ^ ((rv1 & 7) << 4)));
      const s16x8 fmf = *(const s16x8*)(pF + cb);
      o0   = __builtin_amdgcn_mfma_f32_32x32x16_bf16(pa.v, vb0, o0, 0, 0, 0);
      o1   = __builtin_amdgcn_mfma_f32_32x32x16_bf16(pa.v, vb1, o1, 0, 0, 0);
      lacc = __builtin_amdgcn_mfma_f32_32x32x16_bf16(pa.v, fmf, lacc, 0, 0, 0);
    }
    __builtin_amdgcn_s_setprio(0);

    __syncthreads();
    buf ^= 1;
  }

  // epilogue: O rows and lacc rows share the D layout -> lane-local normalize
  unsigned short* ob = attb + ((size_t)(b * S_)) * D_ + h * 64;
#pragma unroll
  for (int r = 0; r < 16; ++r) {
    const float inv = 1.f / lacc[r];
    const int q = q0 + (r & 3) + 8 * (r >> 2) + 4 * hi;
    ob[(size_t)q * D_ + l31]      = f2bf(o0[r] * inv);
    ob[(size_t)q * D_ + 32 + l31] = f2bf(o1[r] * inv);
  }
}

// ---------------------------------------------------------------------------
// proj: out[8192,512] = attb(bf16) @ W via Wt[n][k], MFMA, 128x128 tiles.
// grid (64, 4), 256 threads = 4 waves (2x2), each wave 64x64.
// ---------------------------------------------------------------------------
__global__ __launch_bounds__(256) void proj_mfma_kernel(
    const unsigned short* __restrict__ A, const unsigned short* __restrict__ Wt,
    float* __restrict__ out)
{
  __shared__ unsigned short sA[128 * 64];
  __shared__ unsigned short sB[128 * 64];
  const int m0 = blockIdx.x * 128, n0 = blockIdx.y * 128;
  const int tid = threadIdx.x, w = tid >> 6, l = tid & 63;
  const int l15 = l & 15, l4 = l >> 4;
  const int wm = (w >> 1) * 64, wn = (w & 1) * 64;
  const int swl = ((l & 7) ^ (l >> 3)) * 16;
  const int r8 = l >> 3;

  f32x4 acc[4][4];
#pragma unroll
  for (int i = 0; i < 4; ++i)
#pragma unroll
    for (int j = 0; j < 4; ++j) acc[i][j] = (f32x4){0.f, 0.f, 0.f, 0.f};

  for (int kt = 0; kt < 8; ++kt) {
    const int k0 = kt * 64;
    __syncthreads();
#pragma unroll
    for (int c = 0; c < 4; ++c) {
      const int chunk = w * 4 + c;
      const int r = chunk * 8 + r8;
      gload16((const char*)(A + ((size_t)(m0 + r)) * 512 + k0) + swl,
              (char*)sA + chunk * 1024);
      gload16((const char*)(Wt + ((size_t)(n0 + r)) * 512 + k0) + swl,
              (char*)sB + chunk * 1024);
    }
    __syncthreads();
#pragma unroll
    for (int ks = 0; ks < 2; ++ks) {
      s16x8 af[4], bf_[4];
#pragma unroll
      for (int mb = 0; mb < 4; ++mb) {
        const int row = wm + mb * 16 + l15;
        const int sz = (row & 7) << 4;
        af[mb] = *(const s16x8*)((const char*)sA + row * 128 + ((ks * 64 + l4 * 16) ^ sz));
      }
#pragma unroll
      for (int nb = 0; nb < 4; ++nb) {
        const int row = wn + nb * 16 + l15;
        const int sz = (row & 7) << 4;
        bf_[nb] = *(const s16x8*)((const char*)sB + row * 128 + ((ks * 64 + l4 * 16) ^ sz));
      }
#pragma unroll
      for (int mb = 0; mb < 4; ++mb)
#pragma unroll
        for (int nb = 0; nb < 4; ++nb)
          acc[mb][nb] = __builtin_amdgcn_mfma_f32_16x16x32_bf16(af[mb], bf_[nb], acc[mb][nb], 0, 0, 0);
    }
  }
#pragma unroll
  for (int mb = 0; mb < 4; ++mb)
#pragma unroll
    for (int nb = 0; nb < 4; ++nb)
#pragma unroll
      for (int r = 0; r < 4; ++r)
        out[(size_t)(m0 + wm + mb * 16 + l4 * 4 + r) * 512 + n0 + wn + nb * 16 + l15] =
            acc[mb][nb][r];
}

extern "C" void kernel_launch(void* const* d_in, const int* in_sizes, int n_in,
                              void* d_out, int out_size, void* d_ws, size_t ws_size,
                              hipStream_t stream) {
  const float* q    = (const float*)d_in[0];
  const float* k    = (const float*)d_in[1];
  const float* v    = (const float*)d_in[2];
  const int*   mask = (const int*)d_in[3];
  const float* cut  = (const float*)d_in[4];
  const float* W    = (const float*)d_in[5];
  float* out = (float*)d_out;

  char* ws = (char*)d_ws;
  unsigned short* Kbf  = (unsigned short*)(ws);                    // 8 MB
  unsigned short* Vt   = (unsigned short*)(ws + (8u << 20));       // 8 MB
  unsigned short* attb = (unsigned short*)(ws + (16u << 20));      // 8 MB
  unsigned short* Wt   = (unsigned short*)(ws + (24u << 20));      // 0.5 MB
  unsigned short* fmg  = (unsigned short*)(ws + (25u << 20));      // 16 KB

  conv_kv_kernel<<<dim3(S_ / 64, B_ * H_), 256, 0, stream>>>(k, v, cut, mask, Kbf, Vt, fmg);
  conv_w_kernel<<<dim3(8, 8), 256, 0, stream>>>(W, Wt);
  attn_mfma_kernel<<<dim3(S_ / 128, B_ * H_), 256, 0, stream>>>(q, Kbf, Vt, fmg, attb);
  proj_mfma_kernel<<<dim3(64, 4), 256, 0, stream>>>(attb, Wt, out);
}

// Round 5
// 79.615 us; speedup vs baseline: 20.6758x; 1.0290x over previous
//
#include <hip/hip_runtime.h>
#include <hip/hip_bf16.h>
#include <stdint.h>

#define B_ 4
#define S_ 2048
#define D_ 512
#define H_ 8

typedef __attribute__((ext_vector_type(4))) float f32x4;
typedef __attribute__((ext_vector_type(16))) float f32x16;
typedef __attribute__((ext_vector_type(8))) short s16x8;

__device__ __forceinline__ unsigned short f2bf(float x) {
  union { float f; unsigned u; } v; v.f = x;
  unsigned r = v.u + 0x7FFFu + ((v.u >> 16) & 1u);
  return (unsigned short)(r >> 16);
}

__device__ __forceinline__ unsigned cvtpk_bf16(float lo, float hi) {
  unsigned r;
  asm("v_cvt_pk_bf16_f32 %0, %1, %2" : "=v"(r) : "v"(lo), "v"(hi));
  return r;
}

// v_permlane32_swap_b32: a <- {a.lo, b.lo}, b <- {a.hi, b.hi}
__device__ __forceinline__ void plswap(unsigned &a, unsigned &b) {
  asm("v_permlane32_swap_b32 %0, %1" : "+v"(a), "+v"(b));
}

__device__ __forceinline__ void gload16(const void* g, void* lds) {
  __builtin_amdgcn_global_load_lds(
      (const __attribute__((address_space(1))) void*)g,
      (__attribute__((address_space(3))) void*)lds, 16, 0, 0);
}

// ---------------------------------------------------------------------------
// conv_kv: Kbf[bh][s][dh] = bf16(K); Vt[bh][dh][s] = bf16(V * cutoff * mask);
// fmg[b][s] = bf16(mask ? 1 : 0).  grid (S/64, B*H), 256 threads.
// ---------------------------------------------------------------------------
__global__ __launch_bounds__(256) void conv_kv_kernel(
    const float* __restrict__ km, const float* __restrict__ vm,
    const float* __restrict__ cut, const int* __restrict__ mask,
    unsigned short* __restrict__ Kbf, unsigned short* __restrict__ Vt,
    unsigned short* __restrict__ fmg)
{
  const int st = blockIdx.x, bh = blockIdx.y;
  const int b = bh >> 3, h = bh & 7;
  const int s0 = st * 64;
  __shared__ unsigned short sT[64][68];
  const int tid = threadIdx.x;
#pragma unroll
  for (int j = 0; j < 4; ++j) {
    const int li = tid + j * 256;
    const int r  = li >> 4;
    const int c4 = (li & 15) * 4;
    const size_t g = ((size_t)(b * S_ + s0 + r)) * D_ + h * 64 + c4;
    const float4 kv = *(const float4*)(km + g);
    const float4 vv = *(const float4*)(vm + g);
    const int mk = mask[(size_t)b * S_ + s0 + r];
    const float f = mk ? cut[(size_t)b * S_ + s0 + r] : 0.f;
    *(ushort4*)(Kbf + ((size_t)(bh * S_ + s0 + r)) * 64 + c4) =
        make_ushort4(f2bf(kv.x), f2bf(kv.y), f2bf(kv.z), f2bf(kv.w));
    sT[r][c4 + 0] = f2bf(vv.x * f);
    sT[r][c4 + 1] = f2bf(vv.y * f);
    sT[r][c4 + 2] = f2bf(vv.z * f);
    sT[r][c4 + 3] = f2bf(vv.w * f);
    if (h == 0 && c4 == 0)
      fmg[(size_t)b * S_ + s0 + r] = mk ? (unsigned short)0x3F80 : (unsigned short)0;
  }
  __syncthreads();
#pragma unroll
  for (int j = 0; j < 4; ++j) {
    const int li = tid + j * 256;
    const int dh = li >> 4;
    const int s4 = (li & 15) * 4;
    *(ushort4*)(Vt + ((size_t)(bh * 64 + dh)) * S_ + s0 + s4) =
        make_ushort4(sT[s4 + 0][dh], sT[s4 + 1][dh], sT[s4 + 2][dh], sT[s4 + 3][dh]);
  }
}

// ---------------------------------------------------------------------------
// conv_w: Wt[n][k] = bf16(W[k][n]).  grid (8, 8), 256 threads
// ---------------------------------------------------------------------------
__global__ __launch_bounds__(256) void conv_w_kernel(
    const float* __restrict__ W, unsigned short* __restrict__ Wt)
{
  const int k0 = blockIdx.x * 64, n0 = blockIdx.y * 64;
  __shared__ unsigned short sT[64][68];
  const int tid = threadIdx.x;
#pragma unroll
  for (int j = 0; j < 4; ++j) {
    const int li = tid + j * 256;
    const int r  = li >> 4;
    const int c4 = (li & 15) * 4;
    const float4 wv = *(const float4*)(W + (size_t)(k0 + r) * 512 + n0 + c4);
    sT[r][c4 + 0] = f2bf(wv.x);
    sT[r][c4 + 1] = f2bf(wv.y);
    sT[r][c4 + 2] = f2bf(wv.z);
    sT[r][c4 + 3] = f2bf(wv.w);
  }
  __syncthreads();
#pragma unroll
  for (int j = 0; j < 4; ++j) {
    const int li = tid + j * 256;
    const int n  = li >> 4;
    const int k4 = (li & 15) * 4;
    *(ushort4*)(Wt + (size_t)(n0 + n) * 512 + k0 + k4) =
        make_ushort4(sT[k4 + 0][n], sT[k4 + 1][n], sT[k4 + 2][n], sT[k4 + 3][n]);
  }
}

// ---------------------------------------------------------------------------
// attn: swapped-QK^T, 32x32x16 bf16 MFMA, no max tracking.
// grid (S/128, B*H), 256 threads = 4 waves. Wave w = (qh = w&1, kh = w>>1):
// owns 64 q-rows (2 MFMA streams) and 1024 keys (16 tiles of 64).
// Each K/V fragment read feeds 2 q-streams (halves LDS-read traffic).
// Additive (O,l) partials merged 2-way through LDS in TWO PASSES
// (store kh=0, sync, += kh=1) so the merge buffer fits in 32 KB.
// ---------------------------------------------------------------------------
__global__ __launch_bounds__(256, 2) void attn_mfma_kernel(
    const float* __restrict__ qv, const unsigned short* __restrict__ Kbf,
    const unsigned short* __restrict__ Vt, const unsigned short* __restrict__ fmg,
    unsigned short* __restrict__ attb)
{
  __shared__ unsigned short sK[2][2][4096];   // [kh][buf][key][dh] swizzled, 32 KB
  __shared__ unsigned short sV[2][2][4096];   // [kh][buf][dh][key] swizzled, 32 KB

  const int qt = blockIdx.x, bh = blockIdx.y;
  const int b = bh >> 3, h = bh & 7;
  const int tid = threadIdx.x, w = tid >> 6, l = tid & 63;
  const int l31 = l & 31, hi = l >> 5;
  const int qh = w & 1, kh = w >> 1;
  const int kbase = kh * 1024;

  // Q B-fragments, 2 streams of 32 q-rows, 1/8 scale folded in
  s16x8 qf[2][4];
#pragma unroll
  for (int s = 0; s < 2; ++s) {
    const int qrow = qt * 128 + qh * 64 + s * 32 + l31;
    const float* qp = qv + ((size_t)(b * S_ + qrow)) * D_ + h * 64 + hi * 8;
#pragma unroll
    for (int kc = 0; kc < 4; ++kc) {
      const float4 a0 = *(const float4*)(qp + kc * 16);
      const float4 a1 = *(const float4*)(qp + kc * 16 + 4);
      union { unsigned u[4]; s16x8 v; } t;
      t.u[0] = cvtpk_bf16(a0.x * 0.125f, a0.y * 0.125f);
      t.u[1] = cvtpk_bf16(a0.z * 0.125f, a0.w * 0.125f);
      t.u[2] = cvtpk_bf16(a1.x * 0.125f, a1.y * 0.125f);
      t.u[3] = cvtpk_bf16(a1.z * 0.125f, a1.w * 0.125f);
      qf[s][kc] = t.v;
    }
  }

  f32x16 o00, o01, o10, o11, la0, la1;
#pragma unroll
  for (int r = 0; r < 16; ++r) {
    o00[r] = 0.f; o01[r] = 0.f; o10[r] = 0.f; o11[r] = 0.f;
    la0[r] = 0.f; la1[r] = 0.f;
  }

  const int swl = ((l & 7) ^ (l >> 3)) * 16;
  const int r8  = l >> 3;
  const char* KbfB = (const char*)(Kbf + (size_t)bh * S_ * 64);
  const char* VtB  = (const char*)(Vt + (size_t)bh * 64 * S_);

  auto STAGE = [&](int bufi, int kt) {
    const int k0 = kbase + kt * 64;
#pragma unroll
    for (int c = 0; c < 4; ++c) {
      const int chunk = qh * 4 + c;          // pair {qh=0,qh=1} covers chunks 0..7
      const int row = chunk * 8 + r8;
      gload16(KbfB + (size_t)(k0 + row) * 128 + swl, (char*)sK[kh][bufi] + chunk * 1024);
      gload16(VtB + ((size_t)row * S_ + k0) * 2 + swl, (char*)sV[kh][bufi] + chunk * 1024);
    }
  };

  STAGE(0, 0);
  __syncthreads();

  int buf = 0;
  for (int kt = 0; kt < 16; ++kt) {
    const int k0 = kbase + kt * 64;
    // fmask fragments for this tile (direct from global, L1-broadcast)
    s16x8 fmf[4];
#pragma unroll
    for (int ks = 0; ks < 4; ++ks)
      fmf[ks] = *(const s16x8*)(fmg + (size_t)b * S_ + k0 + ks * 16 + hi * 8);

    if (kt + 1 < 16) STAGE(buf ^ 1, kt + 1);

    const char* pK = (const char*)sK[kh][buf];
    const char* pV = (const char*)sV[kh][buf];

    // QK^T per 32-key half; p = exp(s); pack to bf16 A-fragments in-register
    s16x8 pa[2][4];
#pragma unroll
    for (int k2 = 0; k2 < 2; ++k2) {
      f32x16 sa0, sa1;
#pragma unroll
      for (int r = 0; r < 16; ++r) { sa0[r] = 0.f; sa1[r] = 0.f; }
      __builtin_amdgcn_s_setprio(1);
#pragma unroll
      for (int kc = 0; kc < 4; ++kc) {
        const int row = k2 * 32 + l31;
        const s16x8 kf = *(const s16x8*)(pK + row * 128 +
                          ((kc * 32 + hi * 16) ^ ((row & 7) << 4)));
        sa0 = __builtin_amdgcn_mfma_f32_32x32x16_bf16(kf, qf[0][kc], sa0, 0, 0, 0);
        sa1 = __builtin_amdgcn_mfma_f32_32x32x16_bf16(kf, qf[1][kc], sa1, 0, 0, 0);
      }
      __builtin_amdgcn_s_setprio(0);
      float p0[16], p1[16];
#pragma unroll
      for (int r = 0; r < 16; ++r) { p0[r] = __expf(sa0[r]); p1[r] = __expf(sa1[r]); }
#pragma unroll
      for (int ks = 0; ks < 2; ++ks) {
        const int rb = ks * 8;
        {
          unsigned a0 = cvtpk_bf16(p0[rb + 0], p0[rb + 1]);
          unsigned a1 = cvtpk_bf16(p0[rb + 2], p0[rb + 3]);
          unsigned b0 = cvtpk_bf16(p0[rb + 4], p0[rb + 5]);
          unsigned b1 = cvtpk_bf16(p0[rb + 6], p0[rb + 7]);
          plswap(a0, b0); plswap(a1, b1);
          union { unsigned u[4]; s16x8 v; } t;
          t.u[0] = a0; t.u[1] = a1; t.u[2] = b0; t.u[3] = b1;
          pa[0][k2 * 2 + ks] = t.v;
        }
        {
          unsigned a0 = cvtpk_bf16(p1[rb + 0], p1[rb + 1]);
          unsigned a1 = cvtpk_bf16(p1[rb + 2], p1[rb + 3]);
          unsigned b0 = cvtpk_bf16(p1[rb + 4], p1[rb + 5]);
          unsigned b1 = cvtpk_bf16(p1[rb + 6], p1[rb + 7]);
          plswap(a0, b0); plswap(a1, b1);
          union { unsigned u[4]; s16x8 v; } t;
          t.u[0] = a0; t.u[1] = a1; t.u[2] = b0; t.u[3] = b1;
          pa[1][k2 * 2 + ks] = t.v;
        }
      }
    }

    // PV + l: V fragments read once, shared by both streams (6 MFMA chains)
    __builtin_amdgcn_s_setprio(1);
#pragma unroll
    for (int ks2 = 0; ks2 < 4; ++ks2) {
      const int cb = ks2 * 32 + hi * 16;
      const int rv0 = l31, rv1 = 32 + l31;
      const s16x8 vb0 = *(const s16x8*)(pV + rv0 * 128 + (cb ^ ((rv0 & 7) << 4)));
      const s16x8 vb1 = *(const s16x8*)(pV + rv1 * 128 + (cb ^ ((rv1 & 7) << 4)));
      o00 = __builtin_amdgcn_mfma_f32_32x32x16_bf16(pa[0][ks2], vb0, o00, 0, 0, 0);
      o01 = __builtin_amdgcn_mfma_f32_32x32x16_bf16(pa[0][ks2], vb1, o01, 0, 0, 0);
      o10 = __builtin_amdgcn_mfma_f32_32x32x16_bf16(pa[1][ks2], vb0, o10, 0, 0, 0);
      o11 = __builtin_amdgcn_mfma_f32_32x32x16_bf16(pa[1][ks2], vb1, o11, 0, 0, 0);
      la0 = __builtin_amdgcn_mfma_f32_32x32x16_bf16(pa[0][ks2], fmf[ks2], la0, 0, 0, 0);
      la1 = __builtin_amdgcn_mfma_f32_32x32x16_bf16(pa[1][ks2], fmf[ks2], la1, 0, 0, 0);
    }
    __builtin_amdgcn_s_setprio(0);

    __syncthreads();
    buf ^= 1;
  }

  // ---- 2-way key-split merge, TWO-PASS so buffers fit ----
  // po: [qh][s][half][r][lane] = 8192 floats = 32 KB (aliases sK)
  // pl: [qh][s][hi][r]         = 128 floats        (aliases sV)
  float* po = (float*)&sK[0][0][0];
  float* pl = (float*)&sV[0][0][0];

  if (kh == 0) {
#pragma unroll
    for (int half = 0; half < 2; ++half)
#pragma unroll
      for (int r = 0; r < 16; ++r) {
        po[(((qh * 2 + 0) * 2 + half) * 16 + r) * 64 + l] = (half == 0) ? o00[r] : o01[r];
        po[(((qh * 2 + 1) * 2 + half) * 16 + r) * 64 + l] = (half == 0) ? o10[r] : o11[r];
      }
    if (l31 == 0) {
#pragma unroll
      for (int r = 0; r < 16; ++r) {
        pl[((qh * 2 + 0) * 2 + hi) * 16 + r] = la0[r];
        pl[((qh * 2 + 1) * 2 + hi) * 16 + r] = la1[r];
      }
    }
  }
  __syncthreads();
  if (kh == 1) {
#pragma unroll
    for (int half = 0; half < 2; ++half)
#pragma unroll
      for (int r = 0; r < 16; ++r) {
        po[(((qh * 2 + 0) * 2 + half) * 16 + r) * 64 + l] += (half == 0) ? o00[r] : o01[r];
        po[(((qh * 2 + 1) * 2 + half) * 16 + r) * 64 + l] += (half == 0) ? o10[r] : o11[r];
      }
    if (l31 == 0) {
#pragma unroll
      for (int r = 0; r < 16; ++r) {
        pl[((qh * 2 + 0) * 2 + hi) * 16 + r] += la0[r];
        pl[((qh * 2 + 1) * 2 + hi) * 16 + r] += la1[r];
      }
    }
  }
  __syncthreads();

  // wave w outputs (qm = w&1, sm = w>>1): normalize and store
  const int qm = w & 1, sm = w >> 1;
  unsigned short* ob = attb + ((size_t)b * S_) * D_ + h * 64;
#pragma unroll
  for (int r = 0; r < 16; ++r) {
    const float ls = pl[((qm * 2 + sm) * 2 + hi) * 16 + r];
    const float inv = 1.f / ls;
    const int q = qt * 128 + qm * 64 + sm * 32 + (r & 3) + 8 * (r >> 2) + 4 * hi;
#pragma unroll
    for (int half = 0; half < 2; ++half) {
      const float ov = po[(((qm * 2 + sm) * 2 + half) * 16 + r) * 64 + l];
      ob[(size_t)q * D_ + half * 32 + l31] = f2bf(ov * inv);
    }
  }
}

// ---------------------------------------------------------------------------
// proj: out[8192,512] = attb(bf16) @ W via Wt[n][k], MFMA, 128x128 tiles.
// ---------------------------------------------------------------------------
__global__ __launch_bounds__(256) void proj_mfma_kernel(
    const unsigned short* __restrict__ A, const unsigned short* __restrict__ Wt,
    float* __restrict__ out)
{
  __shared__ unsigned short sA[128 * 64];
  __shared__ unsigned short sB[128 * 64];
  const int m0 = blockIdx.x * 128, n0 = blockIdx.y * 128;
  const int tid = threadIdx.x, w = tid >> 6, l = tid & 63;
  const int l15 = l & 15, l4 = l >> 4;
  const int wm = (w >> 1) * 64, wn = (w & 1) * 64;
  const int swl = ((l & 7) ^ (l >> 3)) * 16;
  const int r8 = l >> 3;

  f32x4 acc[4][4];
#pragma unroll
  for (int i = 0; i < 4; ++i)
#pragma unroll
    for (int j = 0; j < 4; ++j) acc[i][j] = (f32x4){0.f, 0.f, 0.f, 0.f};

  for (int kt = 0; kt < 8; ++kt) {
    const int k0 = kt * 64;
    __syncthreads();
#pragma unroll
    for (int c = 0; c < 4; ++c) {
      const int chunk = w * 4 + c;
      const int r = chunk * 8 + r8;
      gload16((const char*)(A + ((size_t)(m0 + r)) * 512 + k0) + swl,
              (char*)sA + chunk * 1024);
      gload16((const char*)(Wt + ((size_t)(n0 + r)) * 512 + k0) + swl,
              (char*)sB + chunk * 1024);
    }
    __syncthreads();
#pragma unroll
    for (int ks = 0; ks < 2; ++ks) {
      s16x8 af[4], bf_[4];
#pragma unroll
      for (int mb = 0; mb < 4; ++mb) {
        const int row = wm + mb * 16 + l15;
        const int sz = (row & 7) << 4;
        af[mb] = *(const s16x8*)((const char*)sA + row * 128 + ((ks * 64 + l4 * 16) ^ sz));
      }
#pragma unroll
      for (int nb = 0; nb < 4; ++nb) {
        const int row = wn + nb * 16 + l15;
        const int sz = (row & 7) << 4;
        bf_[nb] = *(const s16x8*)((const char*)sB + row * 128 + ((ks * 64 + l4 * 16) ^ sz));
      }
#pragma unroll
      for (int mb = 0; mb < 4; ++mb)
#pragma unroll
        for (int nb = 0; nb < 4; ++nb)
          acc[mb][nb] = __builtin_amdgcn_mfma_f32_16x16x32_bf16(af[mb], bf_[nb], acc[mb][nb], 0, 0, 0);
    }
  }
#pragma unroll
  for (int mb = 0; mb < 4; ++mb)
#pragma unroll
    for (int nb = 0; nb < 4; ++nb)
#pragma unroll
      for (int r = 0; r < 4; ++r)
        out[(size_t)(m0 + wm + mb * 16 + l4 * 4 + r) * 512 + n0 + wn + nb * 16 + l15] =
            acc[mb][nb][r];
}

extern "C" void kernel_launch(void* const* d_in, const int* in_sizes, int n_in,
                              void* d_out, int out_size, void* d_ws, size_t ws_size,
                              hipStream_t stream) {
  const float* q    = (const float*)d_in[0];
  const float* k    = (const float*)d_in[1];
  const float* v    = (const float*)d_in[2];
  const int*   mask = (const int*)d_in[3];
  const float* cut  = (const float*)d_in[4];
  const float* W    = (const float*)d_in[5];
  float* out = (float*)d_out;

  char* ws = (char*)d_ws;
  unsigned short* Kbf  = (unsigned short*)(ws);                    // 8 MB
  unsigned short* Vt   = (unsigned short*)(ws + (8u << 20));       // 8 MB
  unsigned short* attb = (unsigned short*)(ws + (16u << 20));      // 8 MB
  unsigned short* Wt   = (unsigned short*)(ws + (24u << 20));      // 0.5 MB
  unsigned short* fmg  = (unsigned short*)(ws + (25u << 20));      // 16 KB

  conv_kv_kernel<<<dim3(S_ / 64, B_ * H_), 256, 0, stream>>>(k, v, cut, mask, Kbf, Vt, fmg);
  conv_w_kernel<<<dim3(8, 8), 256, 0, stream>>>(W, Wt);
  attn_mfma_kernel<<<dim3(S_ / 128, B_ * H_), 256, 0, stream>>>(q, Kbf, Vt, fmg, attb);
  proj_mfma_kernel<<<dim3(64, 4), 256, 0, stream>>>(attb, Wt, out);
}